// Round 3
// baseline (63.546 us; speedup 1.0000x reference)
//
#include <hip/hip_runtime.h>
#include <hip/hip_bf16.h>

// RipsLayer: gather-only persistence diagram assembly. fp32 I/O per reference.
// Sizes fixed by the reference:
#define F0   8191   // finite dim-0 pairs
#define F1   4096   // finite dim-1 pairs
#define E1   8      // essential dim-1 classes
// Output layout (flat, 24583 fp32 elements):
//   [0 .. 2*F0)              finite_dgm0 [F0,2]  (birth=0, death)
//   [2*F0] = [16382]         essential_dgm0 [1,1] = 0
//   [16383 .. 16383+2*F1)    finite_dgm1 [F1,2]
//   [24575 .. 24583)         essential_dgm1 [E1,1]
//
// Thread layout (one thread per OUTPUT PAIR, not per element):
//   t in [0, F0)        -> dgm0 pair t      (float2 store {0, d})
//   t == F0             -> essential_dgm0 scalar zero
//   t in (F0, F0+F1]    -> dgm1 pair t-F0-1 (int4 index load, 2 scalar stores)
//   t in (F0+F1, +E1]   -> essential_dgm1 scalar
// Total threads = 8191 + 1 + 4096 + 8 = 12296 -> 49 blocks of 256.

__device__ __forceinline__ float pdist3(const float* __restrict__ X, int i, int j) {
    float dx = X[i * 3 + 0] - X[j * 3 + 0];
    float dy = X[i * 3 + 1] - X[j * 3 + 1];
    float dz = X[i * 3 + 2] - X[j * 3 + 2];
    return sqrtf(dx * dx + dy * dy + dz * dz);
}

__global__ void __launch_bounds__(256)
rips_kernel(const float* __restrict__ X,
            const int* __restrict__ idx0f,   // [F0,3]
            const int* __restrict__ idx1f,   // [F1,4]
            const int* __restrict__ idx1e,   // [E1,2]
            float* __restrict__ out) {
    int t = blockIdx.x * blockDim.x + threadIdx.x;

    if (t < F0) {
        // finite_dgm0 pair t: (0, ||X[e1]-X[e2]||), 8B-aligned vector store.
        float d = pdist3(X, idx0f[t * 3 + 1], idx0f[t * 3 + 2]);
        reinterpret_cast<float2*>(out)[t] = make_float2(0.0f, d);
        return;
    }
    if (t == F0) {  // essential_dgm0
        out[2 * F0] = 0.0f;
        return;
    }
    int p = t - F0 - 1;

    if (p < F1) {
        // finite_dgm1 pair p: idx row (b1,b2,d1,d2) via one 16B load.
        int4 q = reinterpret_cast<const int4*>(idx1f)[p];
        float db = pdist3(X, q.x, q.y);
        float dd = pdist3(X, q.z, q.w);
        out[2 * F0 + 1 + 2 * p]     = db;   // region base 16383 is odd -> scalar stores
        out[2 * F0 + 1 + 2 * p + 1] = dd;
        return;
    }
    p -= F1;

    if (p < E1) {  // essential_dgm1
        out[2 * F0 + 1 + 2 * F1 + p] = pdist3(X, idx1e[p * 2 + 0], idx1e[p * 2 + 1]);
    }
}

extern "C" void kernel_launch(void* const* d_in, const int* in_sizes, int n_in,
                              void* d_out, int out_size, void* d_ws, size_t ws_size,
                              hipStream_t stream) {
    const float* X   = (const float*)d_in[0];   // [8192,3] fp32
    const int* idx0f = (const int*)d_in[1];     // [F0,3]
    // d_in[2] = idx0_essential — values unused (output region is zeros)
    const int* idx1f = (const int*)d_in[3];     // [F1,4]
    const int* idx1e = (const int*)d_in[4];     // [E1,2]
    float* out       = (float*)d_out;

    const int total = F0 + 1 + F1 + E1;          // 12296 threads (one per pair)
    const int block = 256;
    const int grid  = (total + block - 1) / block;  // 49
    rips_kernel<<<grid, block, 0, stream>>>(X, idx0f, idx1f, idx1e, out);
}